// Round 1
// baseline (1261.966 us; speedup 1.0000x reference)
//
#include <hip/hip_runtime.h>

// DoubleKVCache: B=2, H=32, S_MAX=8192, D=128, S_NEW=in_sizes[0] (512)
// out0 = kt_cache^T with scatter  [B,H,S_MAX,D]
// out1 = k_cache   with scatter   [B,H,S_MAX,D]
// out2 = v_cache   with scatter   [B,H,S_MAX,D]
//
// v2: 64-row s-tiles, 512-thread blocks (33.8 KB LDS -> 4 blocks/CU, 32 waves/CU).
//     - kt reads: 256 B contiguous per d-row per instruction (was 128 B)
//     - Phase B: each wave instruction covers 2 FULL 512 B output rows ->
//       1 KB contiguous loads AND stores (was 8 x 128 B scattered)
//     - LDS transpose tile XOR-swizzled: writes conflict-free (2-way),
//       v4f-aligned reads preserved
//     - init+scatter of inv merged into one single-block kernel
//     - per-tile inv staged in LDS

#define S_MAXC 8192
#define DC     128
#define BHC    64   // B*H
#define TS     64   // s-rows per tile
#define NTHR   512

typedef __attribute__((ext_vector_type(4))) float v4f;

__global__ void build_inv(const int* __restrict__ pos, int* __restrict__ inv, int n) {
    const int t = threadIdx.x;
    #pragma unroll
    for (int i = t; i < S_MAXC; i += NTHR) inv[i] = -1;
    __syncthreads();
    for (int j = t; j < n; j += NTHR) inv[pos[j]] = j;
}

__global__ void __launch_bounds__(NTHR) fused_kv(
        const v4f* __restrict__ k_val,    // [BH][S_NEW][32]
        const v4f* __restrict__ v_val,
        const v4f* __restrict__ k_cache,  // [BH][S_MAX][32]
        const v4f* __restrict__ v_cache,
        const float* __restrict__ kt_cache, // [BH][D][S_MAX]
        const int*  __restrict__ inv,
        v4f* __restrict__ out0,
        v4f* __restrict__ out1,
        v4f* __restrict__ out2,
        int s_new) {
    // Transposed kt tile: tile[s_local][d_swizzled]. Pitch 132 keeps v4f
    // alignment (132*4 = 528 = 16B-multiple). Column swizzle:
    //   d' = 4*((d>>2) ^ ((row>>2)&7)) + (d&3)
    // -> transpose writes land 2 lanes/bank (free), reads stay b128-aligned.
    __shared__ __align__(16) float tile[TS][132];
    __shared__ int linv[TS];

    const int blk = blockIdx.x;      // 0..8191
    const int bh  = blk >> 7;        // 128 tiles per bh
    const int s0  = (blk & 127) << 6;
    const int t   = threadIdx.x;

    if (t < TS) linv[t] = inv[s0 + t];

    // Phase A: stage 128(d) x 64(s) kt slab into LDS, transposing.
    // 16 lanes per d-row load 256 B contiguous (v4f each).
    {
        const float* ktb = kt_cache + (long)bh * (DC * S_MAXC);
        const int q = t & 15;        // s-quad: s = s0 + 4q .. 4q+3
        const int r = t >> 4;        // 0..31
        const int g = q & 7;         // row>>2 == q for rows 4q+u
        #pragma unroll
        for (int p = 0; p < 4; ++p) {
            const int d = (p << 5) | r;
            v4f vld = __builtin_nontemporal_load(
                (const v4f*)(ktb + (long)d * S_MAXC + s0 + (q << 2)));
            const int dsw = ((((d >> 2) ^ g) << 2) | (d & 3));
            tile[(q << 2) + 0][dsw] = vld.x;
            tile[(q << 2) + 1][dsw] = vld.y;
            tile[(q << 2) + 2][dsw] = vld.z;
            tile[(q << 2) + 3][dsw] = vld.w;
        }
    }
    __syncthreads();

    // Phase B: each wave instruction covers 2 complete rows (1 KB contiguous).
    const int c  = t & 31;           // v4f index within a 512 B row
    const int tt = t >> 5;           // 0..15
    #pragma unroll
    for (int m = 0; m < 4; ++m) {
        const int rl = (m << 4) | tt;        // local row 0..63
        const int s  = s0 + rl;
        const int j  = linv[rl];
        const long row = (long)bh * S_MAXC + s;
        v4f* o0 = out0 + row * 32 + c;
        v4f* o1 = out1 + row * 32 + c;
        v4f* o2 = out2 + row * 32 + c;
        if (j >= 0) {
            // Scattered row: out0 == out1 == k_val row; out2 = v_val row.
            const long vrow = ((long)bh * s_new + j) * 32 + c;
            v4f kx = k_val[vrow];
            v4f vx = v_val[vrow];
            __builtin_nontemporal_store(kx, o0);
            __builtin_nontemporal_store(kx, o1);
            __builtin_nontemporal_store(vx, o2);
        } else {
            v4f kx = __builtin_nontemporal_load(k_cache + row * 32 + c);
            v4f vx = __builtin_nontemporal_load(v_cache + row * 32 + c);
            const int g2 = (rl >> 2) & 7;
            v4f tx = *(const v4f*)&tile[rl][(c ^ g2) << 2];
            __builtin_nontemporal_store(tx, o0);
            __builtin_nontemporal_store(kx, o1);
            __builtin_nontemporal_store(vx, o2);
        }
    }
}

extern "C" void kernel_launch(void* const* d_in, const int* in_sizes, int n_in,
                              void* d_out, int out_size, void* d_ws, size_t ws_size,
                              hipStream_t stream) {
    const int*   input_pos = (const int*)  d_in[0];
    const float* k_val     = (const float*)d_in[1];
    const float* v_val     = (const float*)d_in[2];
    const float* k_cache   = (const float*)d_in[3];
    const float* kt_cache  = (const float*)d_in[4];
    const float* v_cache   = (const float*)d_in[5];
    const int s_new = in_sizes[0];

    const long per_out = (long)BHC * S_MAXC * DC;   // 67,108,864 floats
    float* out0 = (float*)d_out;                    // kt^T
    float* out1 = out0 + per_out;                   // k
    float* out2 = out1 + per_out;                   // v

    int* inv = (int*)d_ws;  // 8192 ints; d_ws re-poisoned each call, rebuild

    build_inv<<<1, NTHR, 0, stream>>>(input_pos, inv, s_new);

    const int n_tiles = BHC * (S_MAXC / TS);        // 8192 blocks
    fused_kv<<<n_tiles, NTHR, 0, stream>>>(
        (const v4f*)k_val, (const v4f*)v_val,
        (const v4f*)k_cache, (const v4f*)v_cache,
        kt_cache, inv,
        (v4f*)out0, (v4f*)out1, (v4f*)out2, s_new);
}